// Round 14
// baseline (1036.116 us; speedup 1.0000x reference)
//
#include <hip/hip_runtime.h>
#include <hip/hip_cooperative_groups.h>
#include <math.h>

namespace cg = cooperative_groups;

#define N_NODES 50000
#define N_EDGES 800000
#define N_GRAPHS 64
#define NEG_SLOPE 0.2f
#define SLOTS 64          // bucket capacity; P(in-degree>64) ~ 1e-20 for Poisson(16)
#define GEMM_UNITS 1563   // ceil(50000/32)
#define NODE_UNITS 12500  // ceil(50000/4)

__device__ __forceinline__ float leaky(float x) {
    return x > 0.f ? x : NEG_SLOPE * x;
}

// ------- GEMM 128-out body: H = X @ W; fused alpha (R10-proven mapping) -------
// Called in a loop in the mega kernel — trailing __syncthreads() guards xs reuse.
__device__ __forceinline__ void gemm128_body(const float* __restrict__ X,
                                             const float* __restrict__ W,
                                             const float* __restrict__ a_src,
                                             const float* __restrict__ a_dst,
                                             float* __restrict__ H,
                                             float* __restrict__ as_,
                                             float* __restrict__ ad_, int bId,
                                             float (*xs)[128]) {
    const int n0 = bId * 32;
    const int tid = threadIdx.x;
    for (int idx = tid; idx < 32 * 32; idx += 256) {
        int r = idx >> 5;
        int q = idx & 31;
        int n = n0 + r;
        float4 v = make_float4(0.f, 0.f, 0.f, 0.f);
        if (n < N_NODES) v = reinterpret_cast<const float4*>(X)[n * 32 + q];
        reinterpret_cast<float4*>(&xs[r][0])[q] = v;
    }
    __syncthreads();

    const int cg_ = tid & 31;
    const int rg = tid >> 5;
    const int c0 = cg_ * 4;
    const int r0 = rg * 4;

    float acc[4][4] = {};
    for (int k = 0; k < 128; k += 4) {
        float4 w[4];
#pragma unroll
        for (int kk = 0; kk < 4; ++kk)
            w[kk] = *reinterpret_cast<const float4*>(&W[(k + kk) * 128 + c0]);
#pragma unroll
        for (int i = 0; i < 4; ++i) {
            float4 xv = *reinterpret_cast<const float4*>(&xs[r0 + i][k]);
            const float xk[4] = {xv.x, xv.y, xv.z, xv.w};
#pragma unroll
            for (int kk = 0; kk < 4; ++kk) {
                acc[i][0] += xk[kk] * w[kk].x;
                acc[i][1] += xk[kk] * w[kk].y;
                acc[i][2] += xk[kk] * w[kk].z;
                acc[i][3] += xk[kk] * w[kk].w;
            }
        }
    }

    const float4 asv = *reinterpret_cast<const float4*>(&a_src[c0]);
    const float4 adv = *reinterpret_cast<const float4*>(&a_dst[c0]);
#pragma unroll
    for (int i = 0; i < 4; ++i) {
        const int n = n0 + r0 + i;
        if (n < N_NODES) {
            float4 o = make_float4(acc[i][0], acc[i][1], acc[i][2], acc[i][3]);
            *reinterpret_cast<float4*>(&H[(size_t)n * 128 + c0]) = o;
        }
        float ps = acc[i][0] * asv.x + acc[i][1] * asv.y + acc[i][2] * asv.z + acc[i][3] * asv.w;
        float pd = acc[i][0] * adv.x + acc[i][1] * adv.y + acc[i][2] * adv.z + acc[i][3] * adv.w;
#pragma unroll
        for (int off = 16; off; off >>= 1) {
            ps += __shfl_xor(ps, off, 64);
            pd += __shfl_xor(pd, off, 64);
        }
        if (cg_ == 0 && n < N_NODES) {
            as_[n] = ps;
            ad_[n] = pd;
        }
    }
    __syncthreads();
}

// ------- GEMM 64-out body, TILE_N=32 (16KB LDS), acc[2][4] per thread -------
__device__ __forceinline__ void gemm64_body(const float* __restrict__ X,
                                            const float* __restrict__ W,
                                            const float* __restrict__ a_src,
                                            const float* __restrict__ a_dst,
                                            float* __restrict__ H,
                                            float* __restrict__ as_,
                                            float* __restrict__ ad_, int bId,
                                            float (*xs)[128]) {
    const int n0 = bId * 32;
    const int tid = threadIdx.x;
    for (int idx = tid; idx < 32 * 32; idx += 256) {
        int r = idx >> 5;
        int q = idx & 31;
        int n = n0 + r;
        float4 v = make_float4(0.f, 0.f, 0.f, 0.f);
        if (n < N_NODES) v = reinterpret_cast<const float4*>(X)[n * 32 + q];
        reinterpret_cast<float4*>(&xs[r][0])[q] = v;
    }
    __syncthreads();

    const int cg_ = tid & 15;
    const int rg = tid >> 4;
    const int c0 = cg_ * 4;
    const int r0 = rg * 2;

    float acc[2][4] = {};
    for (int k = 0; k < 128; k += 4) {
        float4 w[4];
#pragma unroll
        for (int kk = 0; kk < 4; ++kk)
            w[kk] = *reinterpret_cast<const float4*>(&W[(k + kk) * 64 + c0]);
#pragma unroll
        for (int i = 0; i < 2; ++i) {
            float4 xv = *reinterpret_cast<const float4*>(&xs[r0 + i][k]);
            const float xk[4] = {xv.x, xv.y, xv.z, xv.w};
#pragma unroll
            for (int kk = 0; kk < 4; ++kk) {
                acc[i][0] += xk[kk] * w[kk].x;
                acc[i][1] += xk[kk] * w[kk].y;
                acc[i][2] += xk[kk] * w[kk].z;
                acc[i][3] += xk[kk] * w[kk].w;
            }
        }
    }

    const float4 asv = *reinterpret_cast<const float4*>(&a_src[c0]);
    const float4 adv = *reinterpret_cast<const float4*>(&a_dst[c0]);
#pragma unroll
    for (int i = 0; i < 2; ++i) {
        const int n = n0 + r0 + i;
        if (n < N_NODES) {
            float4 o = make_float4(acc[i][0], acc[i][1], acc[i][2], acc[i][3]);
            *reinterpret_cast<float4*>(&H[(size_t)n * 64 + c0]) = o;
        }
        float ps = acc[i][0] * asv.x + acc[i][1] * asv.y + acc[i][2] * asv.z + acc[i][3] * asv.w;
        float pd = acc[i][0] * adv.x + acc[i][1] * adv.y + acc[i][2] * adv.z + acc[i][3] * adv.w;
#pragma unroll
        for (int off = 8; off; off >>= 1) {
            ps += __shfl_xor(ps, off, 64);
            pd += __shfl_xor(pd, off, 64);
        }
        if (cg_ == 0 && n < N_NODES) {
            as_[n] = ps;
            ad_[n] = pd;
        }
    }
    __syncthreads();
}

// ------- gather body (R10-proven, wave per node, no max pass, no LDS) -------
template <int DOUT, bool RELU>
__device__ __forceinline__ void gather_body(const float* __restrict__ H,
                                            const float* __restrict__ as_,
                                            const float* __restrict__ ad_,
                                            const int* __restrict__ cursor,
                                            const int* __restrict__ col,
                                            const float* __restrict__ bias,
                                            float* __restrict__ OUT, int bId) {
    constexpr int NCH4 = DOUT / 4;
    constexpr int SUBS = 64 / NCH4;
    const int node = bId * 4 + ((int)threadIdx.x >> 6);
    if (node >= N_NODES) return;  // device-fn return: exits this body only
    const int l = threadIdx.x & 63;
    const int ch = l & (NCH4 - 1);
    const int sub = l / NCH4;

    const float adn = ad_[node];
    const float sl = leaky(as_[node] + adn);
    const int rs = node << 6;
    const int re = rs + min(cursor[node], SLOTS);

    const float4* __restrict__ H4 = reinterpret_cast<const float4*>(H);
    float4 acc = make_float4(0.f, 0.f, 0.f, 0.f);
    float dsum = 0.f;

    int i = rs + sub;
    for (; i + SUBS < re; i += 2 * SUBS) {
        int s0 = col[i];
        int s1 = col[i + SUBS];
        float e0 = __expf(leaky(as_[s0] + adn));
        float e1 = __expf(leaky(as_[s1] + adn));
        float4 h0 = H4[(size_t)s0 * NCH4 + ch];
        float4 h1 = H4[(size_t)s1 * NCH4 + ch];
        acc.x += e0 * h0.x + e1 * h1.x;
        acc.y += e0 * h0.y + e1 * h1.y;
        acc.z += e0 * h0.z + e1 * h1.z;
        acc.w += e0 * h0.w + e1 * h1.w;
        dsum += e0 + e1;
    }
    if (i < re) {
        int s0 = col[i];
        float e0 = __expf(leaky(as_[s0] + adn));
        float4 h0 = H4[(size_t)s0 * NCH4 + ch];
        acc.x += e0 * h0.x;
        acc.y += e0 * h0.y;
        acc.z += e0 * h0.z;
        acc.w += e0 * h0.w;
        dsum += e0;
    }

#pragma unroll
    for (int off = 32; off >= NCH4; off >>= 1)
        dsum += __shfl_xor(dsum, off, 64);
#pragma unroll
    for (int off = 32; off >= NCH4; off >>= 1) {
        acc.x += __shfl_down(acc.x, off, 64);
        acc.y += __shfl_down(acc.y, off, 64);
        acc.z += __shfl_down(acc.z, off, 64);
        acc.w += __shfl_down(acc.w, off, 64);
    }

    if (l < NCH4) {
        const float e_self = __expf(sl);
        float4 h = H4[(size_t)node * NCH4 + ch];
        acc.x += e_self * h.x;
        acc.y += e_self * h.y;
        acc.z += e_self * h.z;
        acc.w += e_self * h.w;
        const float inv = 1.f / (dsum + e_self);
        const float4 b4 = reinterpret_cast<const float4*>(bias)[ch];
        float4 r;
        r.x = acc.x * inv + b4.x;
        r.y = acc.y * inv + b4.y;
        r.z = acc.z * inv + b4.z;
        r.w = acc.w * inv + b4.w;
        if (RELU) {
            r.x = fmaxf(r.x, 0.f);
            r.y = fmaxf(r.y, 0.f);
            r.z = fmaxf(r.z, 0.f);
            r.w = fmaxf(r.w, 0.f);
        }
        reinterpret_cast<float4*>(OUT)[(size_t)node * NCH4 + ch] = r;
    }
}

// ================= standalone kernels (fallback path) =================
__global__ void fill_kernel(const int* __restrict__ src, const int* __restrict__ dst,
                            int* __restrict__ cursor, int* __restrict__ col, int E) {
    for (int e = blockIdx.x * blockDim.x + threadIdx.x; e < E; e += gridDim.x * blockDim.x) {
        int d = dst[e];
        int p = atomicAdd(&cursor[d], 1);
        if (p < SLOTS) col[(d << 6) + p] = src[e];
    }
}

__global__ __launch_bounds__(256) void gemm128_kernel(const float* __restrict__ X,
                                                      const float* __restrict__ W,
                                                      const float* __restrict__ a_src,
                                                      const float* __restrict__ a_dst,
                                                      float* __restrict__ H,
                                                      float* __restrict__ as_,
                                                      float* __restrict__ ad_) {
    __shared__ __align__(16) float xs[32][128];
    gemm128_body(X, W, a_src, a_dst, H, as_, ad_, blockIdx.x, xs);
}

__global__ __launch_bounds__(256) void gemm64_kernel(const float* __restrict__ X,
                                                     const float* __restrict__ W,
                                                     const float* __restrict__ a_src,
                                                     const float* __restrict__ a_dst,
                                                     float* __restrict__ H,
                                                     float* __restrict__ as_,
                                                     float* __restrict__ ad_) {
    __shared__ __align__(16) float xs[32][128];
    gemm64_body(X, W, a_src, a_dst, H, as_, ad_, blockIdx.x, xs);
}

template <int DOUT, bool RELU>
__global__ __launch_bounds__(256) void gather_kernel(const float* __restrict__ H,
                                                     const float* __restrict__ as_,
                                                     const float* __restrict__ ad_,
                                                     const int* __restrict__ cursor,
                                                     const int* __restrict__ col,
                                                     const float* __restrict__ bias,
                                                     float* __restrict__ OUT) {
    gather_body<DOUT, RELU>(H, as_, ad_, cursor, col, bias, OUT, blockIdx.x);
}

// pool: one block per graph, 4 waves stride rows, LDS reduce; writes all outputs
__global__ __launch_bounds__(256) void pool_kernel(const float* __restrict__ H2,
                                                   const int* __restrict__ batch,
                                                   float* __restrict__ out, int N) {
    __shared__ float sd[256];
    const int g = blockIdx.x;
    const int c = threadIdx.x & 63;
    const int w = threadIdx.x >> 6;
    int lo = 0, hi = N;
    while (lo < hi) {
        int m = (lo + hi) >> 1;
        if (batch[m] < g) lo = m + 1; else hi = m;
    }
    int lo2 = lo, hi2 = N;
    while (lo2 < hi2) {
        int m = (lo2 + hi2) >> 1;
        if (batch[m] < g + 1) lo2 = m + 1; else hi2 = m;
    }
    float s0 = 0.f, s1 = 0.f, s2 = 0.f, s3 = 0.f;
    int n = lo + w;
    for (; n + 12 < lo2; n += 16) {
        s0 += H2[(size_t)n * 64 + c];
        s1 += H2[(size_t)(n + 4) * 64 + c];
        s2 += H2[(size_t)(n + 8) * 64 + c];
        s3 += H2[(size_t)(n + 12) * 64 + c];
    }
    for (; n < lo2; n += 4) s0 += H2[(size_t)n * 64 + c];
    sd[threadIdx.x] = (s0 + s1) + (s2 + s3);
    __syncthreads();
    if (w == 0) out[g * 64 + c] = (sd[c] + sd[c + 64]) + (sd[c + 128] + sd[c + 192]);
}

// ================= cooperative mega kernel =================
__global__ __launch_bounds__(256, 4) void mega_kernel(
    const float* __restrict__ x, const int* __restrict__ esrc, const int* __restrict__ edst,
    const int* __restrict__ batch,
    const float* __restrict__ W0, const float* __restrict__ as0, const float* __restrict__ ad0,
    const float* __restrict__ b0,
    const float* __restrict__ W1, const float* __restrict__ as1, const float* __restrict__ ad1,
    const float* __restrict__ b1,
    const float* __restrict__ W2, const float* __restrict__ as2, const float* __restrict__ ad2,
    const float* __restrict__ b2,
    float* __restrict__ B0, float* __restrict__ H, float* __restrict__ as_,
    float* __restrict__ ad_, int* __restrict__ cursor, int* __restrict__ col,
    int* __restrict__ gstart, float* __restrict__ out) {
    cg::grid_group grid = cg::this_grid();
    __shared__ __align__(16) float xs[32][128];
    const int nb = gridDim.x;
    const int gtid = blockIdx.x * 256 + threadIdx.x;
    const int gstride = nb * 256;

    // P0: zero cursor; precompute graph ranges
    for (int i = gtid; i < N_NODES; i += gstride) cursor[i] = 0;
    if (gtid <= N_GRAPHS) {
        int g = gtid, lo = 0, hi = N_NODES;
        while (lo < hi) {
            int m = (lo + hi) >> 1;
            if (batch[m] < g) lo = m + 1; else hi = m;
        }
        gstart[g] = lo;
    }
    grid.sync();

    // P1: bucketed adjacency fill
    for (int e = gtid; e < N_EDGES; e += gstride) {
        int d = edst[e];
        int p = atomicAdd(&cursor[d], 1);
        if (p < SLOTS) col[(d << 6) + p] = esrc[e];
    }
    grid.sync();

    // P2: gemm0
    for (int b = blockIdx.x; b < GEMM_UNITS; b += nb)
        gemm128_body(x, W0, as0, ad0, H, as_, ad_, b, xs);
    grid.sync();

    // P3: gather0 -> B0 (relu)
    for (int b = blockIdx.x; b < NODE_UNITS; b += nb)
        gather_body<128, true>(H, as_, ad_, cursor, col, b0, B0, b);
    grid.sync();

    // P4: gemm1
    for (int b = blockIdx.x; b < GEMM_UNITS; b += nb)
        gemm128_body(B0, W1, as1, ad1, H, as_, ad_, b, xs);
    grid.sync();

    // P5: gather1 -> B0 (relu)
    for (int b = blockIdx.x; b < NODE_UNITS; b += nb)
        gather_body<128, true>(H, as_, ad_, cursor, col, b1, B0, b);
    grid.sync();

    // P6: gemm2 (64-wide out into H)
    for (int b = blockIdx.x; b < GEMM_UNITS; b += nb)
        gemm64_body(B0, W2, as2, ad2, H, as_, ad_, b, xs);
    grid.sync();

    // P7: gather2 -> B0 (stride 64, no relu)
    for (int b = blockIdx.x; b < NODE_UNITS; b += nb)
        gather_body<64, false>(H, as_, ad_, cursor, col, b2, B0, b);
    grid.sync();

    // P8: pool
    if ((int)blockIdx.x < N_GRAPHS) {
        const int g = blockIdx.x;
        const int c = threadIdx.x & 63;
        const int w = threadIdx.x >> 6;
        const int lo = gstart[g], hi = gstart[g + 1];
        float s0 = 0.f, s1 = 0.f, s2 = 0.f, s3 = 0.f;
        int n = lo + w;
        for (; n + 12 < hi; n += 16) {
            s0 += B0[(size_t)n * 64 + c];
            s1 += B0[(size_t)(n + 4) * 64 + c];
            s2 += B0[(size_t)(n + 8) * 64 + c];
            s3 += B0[(size_t)(n + 12) * 64 + c];
        }
        for (; n < hi; n += 4) s0 += B0[(size_t)n * 64 + c];
        float a = (s0 + s1) + (s2 + s3);
        float* sd = &xs[0][0];
        sd[threadIdx.x] = a;
        __syncthreads();
        if (w == 0) out[g * 64 + c] = (sd[c] + sd[c + 64]) + (sd[c + 128] + sd[c + 192]);
    }
}

extern "C" void kernel_launch(void* const* d_in, const int* in_sizes, int n_in,
                              void* d_out, int out_size, void* d_ws, size_t ws_size,
                              hipStream_t stream) {
    const float* x = (const float*)d_in[0];
    const int* edge_index = (const int*)d_in[1];
    const int* batch = (const int*)d_in[2];
    const float* W0 = (const float*)d_in[3];
    const float* as0 = (const float*)d_in[4];
    const float* ad0 = (const float*)d_in[5];
    const float* b0 = (const float*)d_in[6];
    const float* W1 = (const float*)d_in[7];
    const float* as1 = (const float*)d_in[8];
    const float* ad1 = (const float*)d_in[9];
    const float* b1 = (const float*)d_in[10];
    const float* W2 = (const float*)d_in[11];
    const float* as2 = (const float*)d_in[12];
    const float* ad2 = (const float*)d_in[13];
    const float* b2 = (const float*)d_in[14];

    const int* e_src = edge_index;            // row 0
    const int* e_dst = edge_index + N_EDGES;  // row 1

    // workspace layout
    float* B0 = (float*)d_ws;                 // 50000*128
    float* H = B0 + N_NODES * 128;            // 50000*128
    float* as_ = H + N_NODES * 128;           // 50000
    float* ad_ = as_ + N_NODES;               // 50000
    int* cursor = (int*)(ad_ + N_NODES);      // 50000
    int* col = cursor + N_NODES;              // 50000*64
    int* gstart = col + N_NODES * SLOTS;      // 65
    float* outp = (float*)d_out;

    // runtime-sized cooperative grid (host-only queries; deterministic)
    int blocksPerCU = 0;
    hipOccupancyMaxActiveBlocksPerMultiprocessor(&blocksPerCU, (const void*)mega_kernel, 256, 0);
    int dev = 0, nCU = 0;
    hipGetDevice(&dev);
    hipDeviceGetAttribute(&nCU, hipDeviceAttributeMultiprocessorCount, dev);
    long grid = (long)blocksPerCU * (long)nCU;
    if (grid > 2048) grid = 2048;

    hipError_t cerr = hipErrorUnknown;
    if (grid >= 64) {
        void* args[] = {(void*)&x, (void*)&e_src, (void*)&e_dst, (void*)&batch,
                        (void*)&W0, (void*)&as0, (void*)&ad0, (void*)&b0,
                        (void*)&W1, (void*)&as1, (void*)&ad1, (void*)&b1,
                        (void*)&W2, (void*)&as2, (void*)&ad2, (void*)&b2,
                        (void*)&B0, (void*)&H, (void*)&as_, (void*)&ad_,
                        (void*)&cursor, (void*)&col, (void*)&gstart, (void*)&outp};
        cerr = hipLaunchCooperativeKernel((const void*)mega_kernel, dim3((int)grid), dim3(256),
                                          args, 0, stream);
    }

    if (cerr != hipSuccess) {
        // fallback: R10-proven multi-dispatch pipeline (+ no-memset pool)
        hipMemsetAsync(cursor, 0, N_NODES * sizeof(int), stream);
        fill_kernel<<<2048, 256, 0, stream>>>(e_src, e_dst, cursor, col, N_EDGES);
        gemm128_kernel<<<GEMM_UNITS, 256, 0, stream>>>(x, W0, as0, ad0, H, as_, ad_);
        gather_kernel<128, true><<<NODE_UNITS, 256, 0, stream>>>(H, as_, ad_, cursor, col, b0, B0);
        gemm128_kernel<<<GEMM_UNITS, 256, 0, stream>>>(B0, W1, as1, ad1, H, as_, ad_);
        gather_kernel<128, true><<<NODE_UNITS, 256, 0, stream>>>(H, as_, ad_, cursor, col, b1, B0);
        gemm64_kernel<<<GEMM_UNITS, 256, 0, stream>>>(B0, W2, as2, ad2, H, as_, ad_);
        gather_kernel<64, false><<<NODE_UNITS, 256, 0, stream>>>(H, as_, ad_, cursor, col, b2, B0);
        pool_kernel<<<N_GRAPHS, 256, 0, stream>>>(B0, batch, outp, N_NODES);
    }
}

// Round 15
// 413.285 us; speedup vs baseline: 2.5070x; 2.5070x over previous
//
#include <hip/hip_runtime.h>
#include <math.h>

#define N_NODES 50000
#define N_EDGES 800000
#define N_GRAPHS 64
#define NEG_SLOPE 0.2f
#define SLOTS 64  // bucket capacity; P(in-degree>64) ~ 1e-20 for Poisson(16)

__device__ __forceinline__ float leaky(float x) {
    return x > 0.f ? x : NEG_SLOPE * x;
}

// ---------------- bucketed adjacency build ----------------
__global__ void fill_kernel(const int* __restrict__ src, const int* __restrict__ dst,
                            int* __restrict__ cursor, int* __restrict__ col, int E) {
    for (int e = blockIdx.x * blockDim.x + threadIdx.x; e < E; e += gridDim.x * blockDim.x) {
        int d = dst[e];
        int p = atomicAdd(&cursor[d], 1);
        if (p < SLOTS) col[(d << 6) + p] = src[e];
    }
}

// ------- GEMM: H = X @ W (f32); fused alpha; optional cursor zeroing (layer 0) -------
// ZEROC: first 50000 threads each zero one cursor slot — replaces the memset
// dispatch; kernel-boundary ordering guarantees visibility to the next (fill).
template <int DOUT, bool ZEROC>
__global__ __launch_bounds__(256) void gemm_kernel(const float* __restrict__ X,
                                                   const float* __restrict__ W,
                                                   const float* __restrict__ a_src,
                                                   const float* __restrict__ a_dst,
                                                   float* __restrict__ H,
                                                   float* __restrict__ as_,
                                                   float* __restrict__ ad_,
                                                   int* __restrict__ cursor, int N) {
    if (ZEROC) {
        int zi = blockIdx.x * 256 + threadIdx.x;
        if (zi < N_NODES) cursor[zi] = 0;
    }
    constexpr int DIN = 128;
    constexpr int CG = DOUT / 4;   // col groups of 4
    constexpr int RG = 256 / CG;   // row groups of 4
    constexpr int TILE_N = RG * 4;
    __shared__ __align__(16) float xs[TILE_N][DIN];

    const int n0 = blockIdx.x * TILE_N;
    const int tid = threadIdx.x;

    for (int idx = tid; idx < TILE_N * (DIN / 4); idx += 256) {
        int r = idx / (DIN / 4);
        int q = idx % (DIN / 4);
        int n = n0 + r;
        float4 v = make_float4(0.f, 0.f, 0.f, 0.f);
        if (n < N) v = reinterpret_cast<const float4*>(X)[n * (DIN / 4) + q];
        reinterpret_cast<float4*>(&xs[r][0])[q] = v;
    }
    __syncthreads();

    const int cg = tid % CG;
    const int rg = tid / CG;
    const int c0 = cg * 4;
    const int r0 = rg * 4;

    float acc[4][4] = {};
    for (int k = 0; k < DIN; k += 4) {
        float4 w[4];
#pragma unroll
        for (int kk = 0; kk < 4; ++kk)
            w[kk] = *reinterpret_cast<const float4*>(&W[(k + kk) * DOUT + c0]);
#pragma unroll
        for (int i = 0; i < 4; ++i) {
            float4 xv = *reinterpret_cast<const float4*>(&xs[r0 + i][k]);
            const float xk[4] = {xv.x, xv.y, xv.z, xv.w};
#pragma unroll
            for (int kk = 0; kk < 4; ++kk) {
                acc[i][0] += xk[kk] * w[kk].x;
                acc[i][1] += xk[kk] * w[kk].y;
                acc[i][2] += xk[kk] * w[kk].z;
                acc[i][3] += xk[kk] * w[kk].w;
            }
        }
    }

    const float4 asv = *reinterpret_cast<const float4*>(&a_src[c0]);
    const float4 adv = *reinterpret_cast<const float4*>(&a_dst[c0]);
#pragma unroll
    for (int i = 0; i < 4; ++i) {
        const int n = n0 + r0 + i;
        if (n < N) {
            float4 o = make_float4(acc[i][0], acc[i][1], acc[i][2], acc[i][3]);
            *reinterpret_cast<float4*>(&H[(size_t)n * DOUT + c0]) = o;
        }
        float ps = acc[i][0] * asv.x + acc[i][1] * asv.y + acc[i][2] * asv.z + acc[i][3] * asv.w;
        float pd = acc[i][0] * adv.x + acc[i][1] * adv.y + acc[i][2] * adv.z + acc[i][3] * adv.w;
#pragma unroll
        for (int off = CG / 2; off; off >>= 1) {
            ps += __shfl_xor(ps, off, 64);
            pd += __shfl_xor(pd, off, 64);
        }
        if (cg == 0 && n < N) {
            as_[n] = ps;
            ad_[n] = pd;
        }
    }
}

// ------- fused softmax + gather per dst node (R10-proven, wave per node) -------
template <int DOUT, bool RELU>
__global__ __launch_bounds__(256) void gather_kernel(const float* __restrict__ H,
                                                     const float* __restrict__ as_,
                                                     const float* __restrict__ ad_,
                                                     const int* __restrict__ cursor,
                                                     const int* __restrict__ col,
                                                     const float* __restrict__ bias,
                                                     float* __restrict__ OUT, int N) {
    constexpr int NCH4 = DOUT / 4;               // lanes per edge: 32 or 16
    constexpr int SUBS = 64 / NCH4;              // subgroups: 2 or 4
    const int node = blockIdx.x * 4 + (threadIdx.x >> 6);
    if (node >= N) return;
    const int l = threadIdx.x & 63;
    const int ch = l & (NCH4 - 1);
    const int sub = l / NCH4;

    const float adn = ad_[node];
    const float sl = leaky(as_[node] + adn);
    const int rs = node << 6;
    const int re = rs + min(cursor[node], SLOTS);

    const float4* __restrict__ H4 = reinterpret_cast<const float4*>(H);
    float4 acc = make_float4(0.f, 0.f, 0.f, 0.f);
    float dsum = 0.f;

    int i = rs + sub;
    for (; i + SUBS < re; i += 2 * SUBS) {
        int s0 = col[i];
        int s1 = col[i + SUBS];
        float e0 = __expf(leaky(as_[s0] + adn));
        float e1 = __expf(leaky(as_[s1] + adn));
        float4 h0 = H4[(size_t)s0 * NCH4 + ch];
        float4 h1 = H4[(size_t)s1 * NCH4 + ch];
        acc.x += e0 * h0.x + e1 * h1.x;
        acc.y += e0 * h0.y + e1 * h1.y;
        acc.z += e0 * h0.z + e1 * h1.z;
        acc.w += e0 * h0.w + e1 * h1.w;
        dsum += e0 + e1;
    }
    if (i < re) {
        int s0 = col[i];
        float e0 = __expf(leaky(as_[s0] + adn));
        float4 h0 = H4[(size_t)s0 * NCH4 + ch];
        acc.x += e0 * h0.x;
        acc.y += e0 * h0.y;
        acc.z += e0 * h0.z;
        acc.w += e0 * h0.w;
        dsum += e0;
    }

#pragma unroll
    for (int off = 32; off >= NCH4; off >>= 1)
        dsum += __shfl_xor(dsum, off, 64);
#pragma unroll
    for (int off = 32; off >= NCH4; off >>= 1) {
        acc.x += __shfl_down(acc.x, off, 64);
        acc.y += __shfl_down(acc.y, off, 64);
        acc.z += __shfl_down(acc.z, off, 64);
        acc.w += __shfl_down(acc.w, off, 64);
    }

    if (l < NCH4) {
        const float e_self = __expf(sl);
        float4 h = H4[(size_t)node * NCH4 + ch];
        acc.x += e_self * h.x;
        acc.y += e_self * h.y;
        acc.z += e_self * h.z;
        acc.w += e_self * h.w;
        const float inv = 1.f / (dsum + e_self);
        const float4 b4 = reinterpret_cast<const float4*>(bias)[ch];
        float4 r;
        r.x = acc.x * inv + b4.x;
        r.y = acc.y * inv + b4.y;
        r.z = acc.z * inv + b4.z;
        r.w = acc.w * inv + b4.w;
        if (RELU) {
            r.x = fmaxf(r.x, 0.f);
            r.y = fmaxf(r.y, 0.f);
            r.z = fmaxf(r.z, 0.f);
            r.w = fmaxf(r.w, 0.f);
        }
        reinterpret_cast<float4*>(OUT)[(size_t)node * NCH4 + ch] = r;
    }
}

// ------- pool: one block/graph, 4 waves, binary-search range, LDS reduce -------
// (verified correct as P8 of the R14 mega-kernel run; no memset, no atomics)
__global__ __launch_bounds__(256) void pool_kernel(const float* __restrict__ H2,
                                                   const int* __restrict__ batch,
                                                   float* __restrict__ out, int N) {
    __shared__ float sd[256];
    const int g = blockIdx.x;
    const int c = threadIdx.x & 63;
    const int w = threadIdx.x >> 6;
    int lo = 0, hi = N;
    while (lo < hi) {
        int m = (lo + hi) >> 1;
        if (batch[m] < g) lo = m + 1; else hi = m;
    }
    int lo2 = lo, hi2 = N;
    while (lo2 < hi2) {
        int m = (lo2 + hi2) >> 1;
        if (batch[m] < g + 1) lo2 = m + 1; else hi2 = m;
    }
    float s0 = 0.f, s1 = 0.f, s2 = 0.f, s3 = 0.f;
    int n = lo + w;
    for (; n + 12 < lo2; n += 16) {
        s0 += H2[(size_t)n * 64 + c];
        s1 += H2[(size_t)(n + 4) * 64 + c];
        s2 += H2[(size_t)(n + 8) * 64 + c];
        s3 += H2[(size_t)(n + 12) * 64 + c];
    }
    for (; n < lo2; n += 4) s0 += H2[(size_t)n * 64 + c];
    sd[threadIdx.x] = (s0 + s1) + (s2 + s3);
    __syncthreads();
    if (w == 0) out[g * 64 + c] = (sd[c] + sd[c + 64]) + (sd[c + 128] + sd[c + 192]);
}

extern "C" void kernel_launch(void* const* d_in, const int* in_sizes, int n_in,
                              void* d_out, int out_size, void* d_ws, size_t ws_size,
                              hipStream_t stream) {
    const float* x = (const float*)d_in[0];
    const int* edge_index = (const int*)d_in[1];
    const int* batch = (const int*)d_in[2];
    const float* W0 = (const float*)d_in[3];
    const float* as0 = (const float*)d_in[4];
    const float* ad0 = (const float*)d_in[5];
    const float* b0 = (const float*)d_in[6];
    const float* W1 = (const float*)d_in[7];
    const float* as1 = (const float*)d_in[8];
    const float* ad1 = (const float*)d_in[9];
    const float* b1 = (const float*)d_in[10];
    const float* W2 = (const float*)d_in[11];
    const float* as2 = (const float*)d_in[12];
    const float* ad2 = (const float*)d_in[13];
    const float* b2 = (const float*)d_in[14];

    const int* e_src = edge_index;            // row 0
    const int* e_dst = edge_index + N_EDGES;  // row 1

    // workspace layout (floats)
    float* B0 = (float*)d_ws;                 // 50000*128
    float* H = B0 + N_NODES * 128;            // 50000*128
    float* as_ = H + N_NODES * 128;           // 50000
    float* ad_ = as_ + N_NODES;               // 50000
    int* cursor = (int*)(ad_ + N_NODES);      // 50000 (counts after fill)
    int* col = cursor + N_NODES;              // 50000*64 bucketed adjacency

    const int GEMM128_BLOCKS = (N_NODES + 31) / 32;  // 1563
    const int NODE_BLOCKS = (N_NODES + 3) / 4;       // 12500

    // ---- layer 0 GEMM (also zeroes cursor for fill) ----
    gemm_kernel<128, true><<<GEMM128_BLOCKS, 256, 0, stream>>>(x, W0, as0, ad0, H, as_, ad_,
                                                               cursor, N_NODES);
    // ---- adjacency fill (cursor zeroed by previous kernel) ----
    fill_kernel<<<2048, 256, 0, stream>>>(e_src, e_dst, cursor, col, N_EDGES);
    // ---- gather 0 ----
    gather_kernel<128, true><<<NODE_BLOCKS, 256, 0, stream>>>(H, as_, ad_, cursor, col, b0, B0, N_NODES);

    // ---- layer 1 ----
    gemm_kernel<128, false><<<GEMM128_BLOCKS, 256, 0, stream>>>(B0, W1, as1, ad1, H, as_, ad_,
                                                                cursor, N_NODES);
    gather_kernel<128, true><<<NODE_BLOCKS, 256, 0, stream>>>(H, as_, ad_, cursor, col, b1, B0, N_NODES);

    // ---- layer 2 (64-wide) ----
    gemm_kernel<64, false><<<(N_NODES + 63) / 64, 256, 0, stream>>>(B0, W2, as2, ad2, H, as_, ad_,
                                                                    cursor, N_NODES);
    gather_kernel<64, false><<<NODE_BLOCKS, 256, 0, stream>>>(H, as_, ad_, cursor, col, b2, B0, N_NODES);

    // ---- pool ----
    pool_kernel<<<N_GRAPHS, 256, 0, stream>>>(B0, batch, (float*)d_out, N_NODES);
}